// Round 14
// baseline (247.182 us; speedup 1.0000x reference)
//
#include <hip/hip_runtime.h>
#include <hip/hip_bf16.h>

typedef __attribute__((ext_vector_type(8))) short short8;
typedef __attribute__((ext_vector_type(4))) short short4v;
typedef __attribute__((ext_vector_type(4))) float f32x4;

__device__ __forceinline__ short bf16r(float f) {
    union { float f; unsigned u; } v; v.f = f;
    unsigned u = (v.u + 0x7fffu + ((v.u >> 16) & 1u)) >> 16;
    return (short)u;
}
__device__ __forceinline__ float bf2f(short s) {
    union { unsigned u; float f; } v; v.u = ((unsigned)(unsigned short)s) << 16;
    return v.f;
}

// LDS bank swizzle for [row][32-short] tiles: 16B-slot s -> s ^ fswz(row).
// Involution; applied inverse on the global staging source, forward on ds_read.
__device__ __forceinline__ int fswz(int r) { return (r ^ (r >> 2)) & 3; }

// async global->LDS, 16B per lane; LDS dest = wave-uniform base + lane*16.
__device__ __forceinline__ void gl16(const short* g, short* l) {
    __builtin_amdgcn_global_load_lds(
        (const __attribute__((address_space(1))) unsigned int*)g,
        (__attribute__((address_space(3))) unsigned int*)l, 16, 0, 0);
}

#define M_ROWS 32768
#define KP_A 544      // padded K/stride for stage-a A and Wta (524 real for s=0)
#define NF 512

// All 6 weight transposes in one launch. z in [0,6): z<3 -> Wta[z] (stride 544,
// din 524/512/512), z>=3 -> Wtr[z-3] (stride 512, din 512). Zero-pad k>=din.
__global__ __launch_bounds__(256) void k_wt6(const float* __restrict__ w0,
                                             const float* __restrict__ w1,
                                             const float* __restrict__ w2,
                                             const float* __restrict__ w3,
                                             const float* __restrict__ w4,
                                             const float* __restrict__ w5,
                                             short* __restrict__ wdst) {
    int z = blockIdx.z;
    const float* W = (z == 0) ? w0 : (z == 1) ? w1 : (z == 2) ? w2
                   : (z == 3) ? w3 : (z == 4) ? w4 : w5;
    int din = (z == 0) ? 524 : 512;
    int Kp  = (z < 3) ? KP_A : NF;
    short* Wt = wdst + ((z < 3) ? (size_t)z * NF * KP_A
                                : (size_t)3 * NF * KP_A + (size_t)(z - 3) * NF * NF);
    int kt = blockIdx.x * 32;
    if (kt >= Kp) return;
    int nt = blockIdx.y * 32;
    __shared__ float tile[32][33];
    int tx = threadIdx.x & 31, ty = threadIdx.x >> 5;   // 32 x 8
    #pragma unroll
    for (int r = 0; r < 32; r += 8) {
        int k = kt + ty + r;
        tile[ty + r][tx] = (k < din) ? W[(long)k * NF + nt + tx] : 0.0f;
    }
    __syncthreads();
    #pragma unroll
    for (int r = 0; r < 32; r += 8) {
        int n = nt + ty + r, k = kt + tx;
        Wt[(long)n * Kp + k] = bf16r(tile[tx][ty + r]);
    }
}

__device__ __forceinline__ bool beats(float va, int ia, float vb, int ib) {
    return va > vb || (va == vb && ia < ib);
}

// Fused: per-batch kNN (top-2) + cov features -> A[:, 512:544]  AND
// latent -> A[:, 0:512] bf16 copy (this block's 32 rows), overlapped with
// the VALU-bound scan so the latent HBM traffic is hidden.
// Grid: 16 batches x 64 chunks; block = 8 waves (512 thr), 4 queries/wave.
__global__ __launch_bounds__(512, 8) void k_knncov(const float* __restrict__ pc,
                                                   const float* __restrict__ latent,
                                                   short* __restrict__ A) {
    __shared__ float4 sp[2048];
    __shared__ int ires[64];          // [wid*8 + i*2 + {0,1}]
    int b = blockIdx.x >> 6;
    int chunk = blockIdx.x & 63;      // 32 queries per block
    int t = threadIdx.x;

    // latent copy: this block owns rows [blockIdx.x*32, +32).
    long lrow = (long)blockIdx.x * 32 + (t >> 4);
    int lcol = (t & 15) * 4;
    const float* lsrc = latent + lrow * NF + lcol;
    short* ldst = A + lrow * KP_A + lcol;

    float4 lv0 = *(const float4*)(lsrc);
    float4 lv1 = *(const float4*)(lsrc + 64);
    float4 lv2 = *(const float4*)(lsrc + 128);
    float4 lv3 = *(const float4*)(lsrc + 192);

    const float* p = pc + (long)b * 2048 * 3;
    for (int i = t; i < 2048; i += 512) {
        float x = p[3 * i], y = p[3 * i + 1], z = p[3 * i + 2];
        sp[i] = make_float4(x, y, z, x * x + y * y + z * z);
    }
    __syncthreads();

    {
        short4v s0, s1, s2, s3;
        s0[0] = bf16r(lv0.x); s0[1] = bf16r(lv0.y); s0[2] = bf16r(lv0.z); s0[3] = bf16r(lv0.w);
        s1[0] = bf16r(lv1.x); s1[1] = bf16r(lv1.y); s1[2] = bf16r(lv1.z); s1[3] = bf16r(lv1.w);
        s2[0] = bf16r(lv2.x); s2[1] = bf16r(lv2.y); s2[2] = bf16r(lv2.z); s2[3] = bf16r(lv2.w);
        s3[0] = bf16r(lv3.x); s3[1] = bf16r(lv3.y); s3[2] = bf16r(lv3.z); s3[3] = bf16r(lv3.w);
        *(short4v*)(ldst)       = s0;
        *(short4v*)(ldst + 64)  = s1;
        *(short4v*)(ldst + 128) = s2;
        *(short4v*)(ldst + 192) = s3;
        float4 m0 = *(const float4*)(lsrc + 256);
        float4 m1 = *(const float4*)(lsrc + 320);
        float4 m2 = *(const float4*)(lsrc + 384);
        float4 m3 = *(const float4*)(lsrc + 448);
        s0[0] = bf16r(m0.x); s0[1] = bf16r(m0.y); s0[2] = bf16r(m0.z); s0[3] = bf16r(m0.w);
        s1[0] = bf16r(m1.x); s1[1] = bf16r(m1.y); s1[2] = bf16r(m1.z); s1[3] = bf16r(m1.w);
        s2[0] = bf16r(m2.x); s2[1] = bf16r(m2.y); s2[2] = bf16r(m2.z); s2[3] = bf16r(m2.w);
        s3[0] = bf16r(m3.x); s3[1] = bf16r(m3.y); s3[2] = bf16r(m3.z); s3[3] = bf16r(m3.w);
        *(short4v*)(ldst + 256) = s0;
        *(short4v*)(ldst + 320) = s1;
        *(short4v*)(ldst + 384) = s2;
        *(short4v*)(ldst + 448) = s3;
    }

    int wid = t >> 6, lane = t & 63;
    int nbase = chunk * 32 + wid * 4;

    float qx[4], qy[4], qz[4], qq[4];
    #pragma unroll
    for (int i = 0; i < 4; ++i) {
        float4 q = sp[nbase + i];
        qx[i] = q.x; qy[i] = q.y; qz[i] = q.z; qq[i] = q.w;
    }
    float b0[4], b1[4]; int j0[4], j1[4];
    #pragma unroll
    for (int i = 0; i < 4; ++i) { b0[i] = -INFINITY; b1[i] = -INFINITY; j0[i] = 0; j1[i] = 0; }

    #pragma unroll 2
    for (int it = 0; it < 32; ++it) {
        int m = it * 64 + lane;
        float4 mp = sp[m];
        #pragma unroll
        for (int i = 0; i < 4; ++i) {
            float inner = qx[i] * mp.x + qy[i] * mp.y + qz[i] * mp.z;
            float negd = -((qq[i] - 2.0f * inner) + mp.w);
            bool c0 = negd > b0[i];
            bool c1 = negd > b1[i];
            j1[i] = c0 ? j0[i] : (c1 ? m : j1[i]);
            j0[i] = c0 ? m : j0[i];
            b1[i] = __builtin_amdgcn_fmed3f(negd, b0[i], b1[i]);
            b0[i] = fmaxf(b0[i], negd);
        }
    }

    #pragma unroll
    for (int i = 0; i < 4; ++i) {
        float v0 = b0[i], v1 = b1[i]; int k0 = j0[i], k1 = j1[i];
        #pragma unroll
        for (int off = 1; off < 64; off <<= 1) {
            float w0 = __shfl_xor(v0, off, 64), w1 = __shfl_xor(v1, off, 64);
            int   l0 = __shfl_xor(k0, off, 64), l1 = __shfl_xor(k1, off, 64);
            float n0v, n1v; int n0i, n1i;
            if (beats(v0, k0, w0, l0)) {
                n0v = v0; n0i = k0;
                if (beats(w0, l0, v1, k1)) { n1v = w0; n1i = l0; } else { n1v = v1; n1i = k1; }
            } else {
                n0v = w0; n0i = l0;
                if (beats(v0, k0, w1, l1)) { n1v = v0; n1i = k0; } else { n1v = w1; n1i = l1; }
            }
            v0 = n0v; k0 = n0i; v1 = n1v; k1 = n1i;
        }
        if (lane == 0) {
            ires[wid * 8 + i * 2]     = k0;
            ires[wid * 8 + i * 2 + 1] = k1;
        }
    }
    __syncthreads();
    if (t < 32) {
        int k0 = ires[(t >> 2) * 8 + (t & 3) * 2];
        int k1 = ires[(t >> 2) * 8 + (t & 3) * 2 + 1];
        int n = chunk * 32 + t;
        float4 qn = sp[n];
        float4 p0 = sp[k0];
        float4 p1 = sp[k1];
        long row = (long)b * 2048 + n;
        short vals[32];
        vals[0] = bf16r(qn.x); vals[1] = bf16r(qn.y); vals[2] = bf16r(qn.z);
        float ou[9] = {p0.x * p1.x, p0.x * p1.y, p0.x * p1.z,
                       p0.y * p1.x, p0.y * p1.y, p0.y * p1.z,
                       p0.z * p1.x, p0.z * p1.y, p0.z * p1.z};
        #pragma unroll
        for (int q = 0; q < 9; ++q) vals[3 + q] = bf16r(ou[q]);
        #pragma unroll
        for (int q = 12; q < 32; ++q) vals[q] = 0;
        short* dst = A + row * KP_A + NF;
        #pragma unroll
        for (int q = 0; q < 4; ++q)
            *(short8*)(dst + q * 8) = *(short8*)(vals + q * 8);
    }
}

// out = bo (add=0) or out += bo (add=1)
__global__ __launch_bounds__(256) void k_setbo(float* __restrict__ out,
                                               const float* __restrict__ bo, int add) {
    int i = blockIdx.x * 256 + threadIdx.x;
    float v = bo[0];
    out[i] = add ? (out[i] + v) : v;
}

// GEMM: 256x256 tile, 8 waves (2x4), per-wave 128x64 output, BK=32,
// 3-buffer LDS pipeline with counted vmcnt (never 0 mid-loop),
// global_load_lds width-16, XOR-swizzled staging, setprio around MFMA,
// bijective XCD block swizzle. Same sync invariants as round-8 (counts: 4
// gl16/wave/tile -> vmcnt(4)). LDS 96KB -> 1 block/CU; ~0.375 KB LDS/MFMA.
#define BM 256
#define BN 256
#define BK 32

__global__ __launch_bounds__(512, 2) void k_gemm(const short* __restrict__ A,
                                                 const short* __restrict__ Bt,
                                                 const float* __restrict__ bias,
                                                 const short* __restrict__ Res,
                                                 short* __restrict__ C,
                                                 const float* __restrict__ wov,
                                                 float* __restrict__ outp,
                                                 const float* __restrict__ wex,
                                                 const float* __restrict__ outv,
                                                 const float* __restrict__ bov,
                                                 int lda, int kend) {
    __shared__ __align__(16) short As[3][BM * BK];   // 3 x 16KB
    __shared__ __align__(16) short Bs[3][BN * BK];   // 3 x 16KB
    // XCD swizzle (nwg % 8 == 0, bijective): XCD k gets a contiguous wgid chunk.
    int nwg = gridDim.x;
    int orig = blockIdx.x;
    int wgid = (orig & 7) * (nwg >> 3) + (orig >> 3);
    int bm = wgid >> 1, bn = wgid & 1;    // 2 bn-tiles (N=512) per bm
    int t = threadIdx.x, lane = t & 63, wid = t >> 6;   // wid 0..7
    int wm = wid >> 2, wn = wid & 3;      // 2 x 4 wave grid
    f32x4 acc[8][4] = {};
    const long arow0 = (long)bm * BM, brow0 = (long)bn * BN;
    int l15 = lane & 15;

    // staging: wave wid owns chunk pair {2w, 2w+1} of BOTH As and Bs.
    // 1KB chunk c: lane l -> row c*16 + (l>>2), 16B-slot l&3 (linear dest);
    // global source slot = (l&3) ^ fswz(row).
    int rc0 = (wid * 2) * 16 + (lane >> 2);
    int rc1 = (wid * 2 + 1) * 16 + (lane >> 2);
    int ks0 = ((lane & 3) ^ fswz(rc0)) * 8;
    int ks1 = ((lane & 3) ^ fswz(rc1)) * 8;
    long aoff0 = (arow0 + rc0) * (long)lda + ks0;
    long aoff1 = (arow0 + rc1) * (long)lda + ks1;
    long boff0 = (brow0 + rc0) * (long)lda + ks0;
    long boff1 = (brow0 + rc1) * (long)lda + ks1;
    int cb0 = (wid * 2) * 512;
    int cb1 = (wid * 2 + 1) * 512;

    // fragment read offsets (shorts): logical slot (lane>>4) ^ fswz(row)
    int ra[8], rb[4];
    #pragma unroll
    for (int i = 0; i < 8; ++i) {
        int rA = wm * 128 + i * 16 + l15;
        ra[i] = rA * 32 + (((lane >> 4) ^ fswz(rA)) * 8);
    }
    #pragma unroll
    for (int j = 0; j < 4; ++j) {
        int rB = wn * 64 + j * 16 + l15;
        rb[j] = rB * 32 + (((lane >> 4) ^ fswz(rB)) * 8);
    }

#define STAGE(bufi, ktoff) do { \
        gl16(A  + aoff0 + (ktoff), &As[bufi][cb0]); \
        gl16(A  + aoff1 + (ktoff), &As[bufi][cb1]); \
        gl16(Bt + boff0 + (ktoff), &Bs[bufi][cb0]); \
        gl16(Bt + boff1 + (ktoff), &Bs[bufi][cb1]); \
    } while (0)

    int nt = kend / BK;
    // prologue: tiles 0,1 in flight (4 loads each); wait tile 0 only.
    STAGE(0, 0);
    STAGE(1, BK);
    asm volatile("s_waitcnt vmcnt(4)" ::: "memory");
    __builtin_amdgcn_sched_barrier(0);
    __builtin_amdgcn_s_barrier();

    int cur = 0;
    for (int kt = 0; kt < nt; ++kt) {
        short8 fa[8], fb[4];
        #pragma unroll
        for (int i = 0; i < 8; ++i) fa[i] = *(const short8*)&As[cur][ra[i]];
        #pragma unroll
        for (int j = 0; j < 4; ++j) fb[j] = *(const short8*)&Bs[cur][rb[j]];
        if (kt + 2 < nt) {
            // overwrite buffer (kt+2)%3 == (kt-1)%3: its readers finished
            // before iteration kt-1's barrier, which all waves have passed.
            int stg = (cur >= 1) ? cur - 1 : 2;
            STAGE(stg, (kt + 2) * BK);
            // wait: tile-(kt+1) loads landed (oldest 4 of 8) + my ds_reads
            // done (so others may overwrite As[cur] next iteration).
            asm volatile("s_waitcnt vmcnt(4) lgkmcnt(0)" ::: "memory");
            __builtin_amdgcn_sched_barrier(0);
            __builtin_amdgcn_s_barrier();
        } else if (kt + 1 < nt) {
            asm volatile("s_waitcnt vmcnt(0) lgkmcnt(0)" ::: "memory");
            __builtin_amdgcn_sched_barrier(0);
            __builtin_amdgcn_s_barrier();
        }
        __builtin_amdgcn_s_setprio(1);
        #pragma unroll
        for (int i = 0; i < 8; ++i)
            #pragma unroll
            for (int j = 0; j < 4; ++j)
                acc[i][j] = __builtin_amdgcn_mfma_f32_16x16x32_bf16(fa[i], fb[j], acc[i][j], 0, 0, 0);
        __builtin_amdgcn_s_setprio(0);
        cur = (cur >= 2) ? 0 : cur + 1;
    }
#undef STAGE

    int rq4 = (lane >> 4) * 4;
    if (wov == nullptr) {
        #pragma unroll
        for (int i = 0; i < 8; ++i) {
            #pragma unroll
            for (int j = 0; j < 4; ++j) {
                int col = bn * BN + wn * 64 + j * 16 + l15;
                float bval = bias[col];
                float wexv = wex ? wex[col] : 0.0f;
                #pragma unroll
                for (int r = 0; r < 4; ++r) {
                    long row = arow0 + wm * 128 + i * 16 + rq4 + r;
                    float v = acc[i][j][r] + bval;
                    if (wex) v += outv[row] * wexv;
                    v = fmaxf(v, 0.0f);
                    C[row * NF + col] = bf16r(v);
                }
            }
        }
    } else {
        float wv[4], bv[4];
        #pragma unroll
        for (int j = 0; j < 4; ++j) {
            int col = bn * BN + wn * 64 + j * 16 + l15;
            wv[j] = wov[col];
            bv[j] = bias[col];
        }
        float boadd = (bov != nullptr && wn == 0 && bn == 0) ? bov[0] : 0.0f;
        #pragma unroll
        for (int i = 0; i < 8; ++i) {
            #pragma unroll
            for (int r = 0; r < 4; ++r) {
                long row = arow0 + wm * 128 + i * 16 + rq4 + r;
                float s = 0.0f;
                #pragma unroll
                for (int j = 0; j < 4; ++j) {
                    int col = bn * BN + wn * 64 + j * 16 + l15;
                    float v = acc[i][j][r] + bv[j] + bf2f(Res[row * NF + col]);
                    v = fmaxf(v, 0.0f);
                    s += v * wv[j];
                }
                s += __shfl_xor(s, 1, 64);
                s += __shfl_xor(s, 2, 64);
                s += __shfl_xor(s, 4, 64);
                s += __shfl_xor(s, 8, 64);
                if (l15 == 0) atomicAdd(outp + row, s + boadd);
            }
        }
    }
}

extern "C" void kernel_launch(void* const* d_in, const int* in_sizes, int n_in,
                              void* d_out, int out_size, void* d_ws, size_t ws_size,
                              hipStream_t stream) {
    (void)in_sizes; (void)n_in; (void)out_size; (void)ws_size;
    const float* latent = (const float*)d_in[0];
    const float* pc     = (const float*)d_in[1];
    const float *wa[3], *ba[3], *wr[3], *br[3], *wo[3], *bo[3];
    for (int s = 0; s < 3; ++s) {
        int base = 2 + s * 6;
        wa[s] = (const float*)d_in[base + 0];
        ba[s] = (const float*)d_in[base + 1];
        wr[s] = (const float*)d_in[base + 2];
        br[s] = (const float*)d_in[base + 3];
        wo[s] = (const float*)d_in[base + 4];
        bo[s] = (const float*)d_in[base + 5];
    }

    char* ws = (char*)d_ws;
    size_t off = 0;
    short* A  = (short*)(ws + off); off += (size_t)M_ROWS * KP_A * 2;   // 35.7 MB
    short* H1 = (short*)(ws + off); off += (size_t)M_ROWS * NF * 2;     // 33.6 MB
    short* Wbase = (short*)(ws + off);
    short *Wta[3], *Wtr[3];
    for (int s = 0; s < 3; ++s) { Wta[s] = Wbase + (size_t)s * NF * KP_A; }
    for (int s = 0; s < 3; ++s) { Wtr[s] = Wbase + (size_t)3 * NF * KP_A + (size_t)s * NF * NF; }
    float* out = (float*)d_out;

    dim3 gw((KP_A + 31) / 32, NF / 32, 6);
    k_wt6<<<gw, 256, 0, stream>>>(wa[0], wa[1], wa[2], wr[0], wr[1], wr[2], Wbase);
    k_knncov<<<1024, 512, 0, stream>>>(pc, latent, A);
    k_setbo<<<M_ROWS / 256, 256, 0, stream>>>(out, bo[0], 0);

    int nwg = (M_ROWS / BM) * (NF / BN);   // 256, %8==0
    for (int s = 0; s < 3; ++s) {
        if (s == 0) {
            k_gemm<<<nwg, 512, 0, stream>>>(A, Wta[0], ba[0], nullptr, H1,
                                            nullptr, nullptr, nullptr, nullptr,
                                            nullptr, KP_A, KP_A);
        } else {
            // K=512 + rank-1 (out[row] * wa_row512[col]) in epilogue
            k_gemm<<<nwg, 512, 0, stream>>>(A, Wta[s], ba[s], nullptr, H1,
                                            nullptr, nullptr,
                                            wa[s] + (size_t)NF * NF, out,
                                            nullptr, KP_A, NF);
        }
        k_gemm<<<nwg, 512, 0, stream>>>(H1, Wtr[s], br[s], H1, nullptr,
                                        wo[s], out, nullptr, nullptr,
                                        s > 0 ? bo[s] : nullptr, NF, NF);
    }
}

// Round 15
// 209.009 us; speedup vs baseline: 1.1826x; 1.1826x over previous
//
#include <hip/hip_runtime.h>
#include <hip/hip_bf16.h>

typedef __attribute__((ext_vector_type(8))) short short8;
typedef __attribute__((ext_vector_type(4))) short short4v;
typedef __attribute__((ext_vector_type(4))) float f32x4;

__device__ __forceinline__ short bf16r(float f) {
    union { float f; unsigned u; } v; v.f = f;
    unsigned u = (v.u + 0x7fffu + ((v.u >> 16) & 1u)) >> 16;
    return (short)u;
}
__device__ __forceinline__ float bf2f(short s) {
    union { unsigned u; float f; } v; v.u = ((unsigned)(unsigned short)s) << 16;
    return v.f;
}

// LDS bank swizzle for [row][32-short] tiles: 16B-slot s -> s ^ fswz(row).
// Involution; applied inverse on the global staging source, forward on ds_read.
__device__ __forceinline__ int fswz(int r) { return (r ^ (r >> 2)) & 3; }

// async global->LDS, 16B per lane; LDS dest = wave-uniform base + lane*16.
__device__ __forceinline__ void gl16(const short* g, short* l) {
    __builtin_amdgcn_global_load_lds(
        (const __attribute__((address_space(1))) unsigned int*)g,
        (__attribute__((address_space(3))) unsigned int*)l, 16, 0, 0);
}

#define M_ROWS 32768
#define KP_A 544      // padded K/stride for stage-a A and Wta (524 real for s=0)
#define NF 512

// All 6 weight transposes in one launch. z in [0,6): z<3 -> Wta[z] (stride 544,
// din 524/512/512), z>=3 -> Wtr[z-3] (stride 512, din 512). Zero-pad k>=din.
__global__ __launch_bounds__(256) void k_wt6(const float* __restrict__ w0,
                                             const float* __restrict__ w1,
                                             const float* __restrict__ w2,
                                             const float* __restrict__ w3,
                                             const float* __restrict__ w4,
                                             const float* __restrict__ w5,
                                             short* __restrict__ wdst) {
    int z = blockIdx.z;
    const float* W = (z == 0) ? w0 : (z == 1) ? w1 : (z == 2) ? w2
                   : (z == 3) ? w3 : (z == 4) ? w4 : w5;
    int din = (z == 0) ? 524 : 512;
    int Kp  = (z < 3) ? KP_A : NF;
    short* Wt = wdst + ((z < 3) ? (size_t)z * NF * KP_A
                                : (size_t)3 * NF * KP_A + (size_t)(z - 3) * NF * NF);
    int kt = blockIdx.x * 32;
    if (kt >= Kp) return;
    int nt = blockIdx.y * 32;
    __shared__ float tile[32][33];
    int tx = threadIdx.x & 31, ty = threadIdx.x >> 5;   // 32 x 8
    #pragma unroll
    for (int r = 0; r < 32; r += 8) {
        int k = kt + ty + r;
        tile[ty + r][tx] = (k < din) ? W[(long)k * NF + nt + tx] : 0.0f;
    }
    __syncthreads();
    #pragma unroll
    for (int r = 0; r < 32; r += 8) {
        int n = nt + ty + r, k = kt + tx;
        Wt[(long)n * Kp + k] = bf16r(tile[tx][ty + r]);
    }
}

__device__ __forceinline__ bool beats(float va, int ia, float vb, int ib) {
    return va > vb || (va == vb && ia < ib);
}

// Fused: per-batch kNN (top-2) + cov features -> A[:, 512:544]  AND
// latent -> A[:, 0:512] bf16 copy (this block's 32 rows)  AND
// out[row] = bo (seeding stage-1's accumulator), all overlapped with the
// VALU-bound scan. Grid: 16 batches x 64 chunks; 8 waves, 4 queries/wave.
__global__ __launch_bounds__(512, 8) void k_knncov(const float* __restrict__ pc,
                                                   const float* __restrict__ latent,
                                                   short* __restrict__ A,
                                                   const float* __restrict__ bo0,
                                                   float* __restrict__ outp) {
    __shared__ float4 sp[2048];
    __shared__ int ires[64];          // [wid*8 + i*2 + {0,1}]
    int b = blockIdx.x >> 6;
    int chunk = blockIdx.x & 63;      // 32 queries per block
    int t = threadIdx.x;

    // latent copy: this block owns rows [blockIdx.x*32, +32).
    long lrow = (long)blockIdx.x * 32 + (t >> 4);
    int lcol = (t & 15) * 4;
    const float* lsrc = latent + lrow * NF + lcol;
    short* ldst = A + lrow * KP_A + lcol;

    float4 lv0 = *(const float4*)(lsrc);
    float4 lv1 = *(const float4*)(lsrc + 64);
    float4 lv2 = *(const float4*)(lsrc + 128);
    float4 lv3 = *(const float4*)(lsrc + 192);

    const float* p = pc + (long)b * 2048 * 3;
    for (int i = t; i < 2048; i += 512) {
        float x = p[3 * i], y = p[3 * i + 1], z = p[3 * i + 2];
        sp[i] = make_float4(x, y, z, x * x + y * y + z * z);
    }
    __syncthreads();

    {
        short4v s0, s1, s2, s3;
        s0[0] = bf16r(lv0.x); s0[1] = bf16r(lv0.y); s0[2] = bf16r(lv0.z); s0[3] = bf16r(lv0.w);
        s1[0] = bf16r(lv1.x); s1[1] = bf16r(lv1.y); s1[2] = bf16r(lv1.z); s1[3] = bf16r(lv1.w);
        s2[0] = bf16r(lv2.x); s2[1] = bf16r(lv2.y); s2[2] = bf16r(lv2.z); s2[3] = bf16r(lv2.w);
        s3[0] = bf16r(lv3.x); s3[1] = bf16r(lv3.y); s3[2] = bf16r(lv3.z); s3[3] = bf16r(lv3.w);
        *(short4v*)(ldst)       = s0;
        *(short4v*)(ldst + 64)  = s1;
        *(short4v*)(ldst + 128) = s2;
        *(short4v*)(ldst + 192) = s3;
        float4 m0 = *(const float4*)(lsrc + 256);
        float4 m1 = *(const float4*)(lsrc + 320);
        float4 m2 = *(const float4*)(lsrc + 384);
        float4 m3 = *(const float4*)(lsrc + 448);
        s0[0] = bf16r(m0.x); s0[1] = bf16r(m0.y); s0[2] = bf16r(m0.z); s0[3] = bf16r(m0.w);
        s1[0] = bf16r(m1.x); s1[1] = bf16r(m1.y); s1[2] = bf16r(m1.z); s1[3] = bf16r(m1.w);
        s2[0] = bf16r(m2.x); s2[1] = bf16r(m2.y); s2[2] = bf16r(m2.z); s2[3] = bf16r(m2.w);
        s3[0] = bf16r(m3.x); s3[1] = bf16r(m3.y); s3[2] = bf16r(m3.z); s3[3] = bf16r(m3.w);
        *(short4v*)(ldst + 256) = s0;
        *(short4v*)(ldst + 320) = s1;
        *(short4v*)(ldst + 384) = s2;
        *(short4v*)(ldst + 448) = s3;
    }

    int wid = t >> 6, lane = t & 63;
    int nbase = chunk * 32 + wid * 4;

    float qx[4], qy[4], qz[4], qq[4];
    #pragma unroll
    for (int i = 0; i < 4; ++i) {
        float4 q = sp[nbase + i];
        qx[i] = q.x; qy[i] = q.y; qz[i] = q.z; qq[i] = q.w;
    }
    float b0[4], b1[4]; int j0[4], j1[4];
    #pragma unroll
    for (int i = 0; i < 4; ++i) { b0[i] = -INFINITY; b1[i] = -INFINITY; j0[i] = 0; j1[i] = 0; }

    #pragma unroll 2
    for (int it = 0; it < 32; ++it) {
        int m = it * 64 + lane;
        float4 mp = sp[m];
        #pragma unroll
        for (int i = 0; i < 4; ++i) {
            float inner = qx[i] * mp.x + qy[i] * mp.y + qz[i] * mp.z;
            float negd = -((qq[i] - 2.0f * inner) + mp.w);
            bool c0 = negd > b0[i];
            bool c1 = negd > b1[i];
            j1[i] = c0 ? j0[i] : (c1 ? m : j1[i]);
            j0[i] = c0 ? m : j0[i];
            b1[i] = __builtin_amdgcn_fmed3f(negd, b0[i], b1[i]);
            b0[i] = fmaxf(b0[i], negd);
        }
    }

    #pragma unroll
    for (int i = 0; i < 4; ++i) {
        float v0 = b0[i], v1 = b1[i]; int k0 = j0[i], k1 = j1[i];
        #pragma unroll
        for (int off = 1; off < 64; off <<= 1) {
            float w0 = __shfl_xor(v0, off, 64), w1 = __shfl_xor(v1, off, 64);
            int   l0 = __shfl_xor(k0, off, 64), l1 = __shfl_xor(k1, off, 64);
            float n0v, n1v; int n0i, n1i;
            if (beats(v0, k0, w0, l0)) {
                n0v = v0; n0i = k0;
                if (beats(w0, l0, v1, k1)) { n1v = w0; n1i = l0; } else { n1v = v1; n1i = k1; }
            } else {
                n0v = w0; n0i = l0;
                if (beats(v0, k0, w1, l1)) { n1v = v0; n1i = k0; } else { n1v = w1; n1i = l1; }
            }
            v0 = n0v; k0 = n0i; v1 = n1v; k1 = n1i;
        }
        if (lane == 0) {
            ires[wid * 8 + i * 2]     = k0;
            ires[wid * 8 + i * 2 + 1] = k1;
        }
    }
    __syncthreads();
    // tail: 32 threads write cov features; 32 threads seed out[row] = bo.
    if (t < 32) {
        int k0 = ires[(t >> 2) * 8 + (t & 3) * 2];
        int k1 = ires[(t >> 2) * 8 + (t & 3) * 2 + 1];
        int n = chunk * 32 + t;
        float4 qn = sp[n];
        float4 p0 = sp[k0];
        float4 p1 = sp[k1];
        long row = (long)b * 2048 + n;
        short vals[32];
        vals[0] = bf16r(qn.x); vals[1] = bf16r(qn.y); vals[2] = bf16r(qn.z);
        float ou[9] = {p0.x * p1.x, p0.x * p1.y, p0.x * p1.z,
                       p0.y * p1.x, p0.y * p1.y, p0.y * p1.z,
                       p0.z * p1.x, p0.z * p1.y, p0.z * p1.z};
        #pragma unroll
        for (int q = 0; q < 9; ++q) vals[3 + q] = bf16r(ou[q]);
        #pragma unroll
        for (int q = 12; q < 32; ++q) vals[q] = 0;
        short* dst = A + row * KP_A + NF;
        #pragma unroll
        for (int q = 0; q < 4; ++q)
            *(short8*)(dst + q * 8) = *(short8*)(vals + q * 8);
    } else if (t < 64) {
        // out rows of this block: blockIdx.x*32 .. +32 (disjoint per block)
        outp[(long)blockIdx.x * 32 + (t - 32)] = bo0[0];
    }
}

// GEMM: 256x128 tile, 8 waves (512 thr), BK=32, 3-buffer LDS pipeline with
// counted vmcnt (never 0 mid-loop), global_load_lds width-16, XOR-swizzled
// staging, setprio around MFMA, bijective XCD block swizzle.
// (round-13 proven version: 16x16x32 MFMA, 4x4 frags, 2 blocks/CU)
#define BM 256
#define BN 128
#define BK 32

__global__ __launch_bounds__(512, 4) void k_gemm(const short* __restrict__ A,
                                                 const short* __restrict__ Bt,
                                                 const float* __restrict__ bias,
                                                 const short* __restrict__ Res,
                                                 short* __restrict__ C,
                                                 const float* __restrict__ wov,
                                                 float* __restrict__ outp,
                                                 const float* __restrict__ wex,
                                                 const float* __restrict__ outv,
                                                 const float* __restrict__ bov,
                                                 int lda, int kend) {
    __shared__ __align__(16) short As[3][BM * BK];   // 3 x 16KB
    __shared__ __align__(16) short Bs[3][BN * BK];   // 3 x 8KB
    // XCD swizzle (nwg % 8 == 0, bijective): XCD k gets a contiguous wgid chunk.
    int nwg = gridDim.x;
    int orig = blockIdx.x;
    int wgid = (orig & 7) * (nwg >> 3) + (orig >> 3);
    int bm = wgid >> 2, bn = wgid & 3;    // 4 bn-tiles (N=512) per bm
    int t = threadIdx.x, lane = t & 63, wid = t >> 6;   // wid 0..7
    int wm = wid >> 1, wn = wid & 1;
    f32x4 acc[4][4] = {};
    const long arow0 = (long)bm * BM, brow0 = (long)bn * BN;
    int l15 = lane & 15;

    // staging: wave wid owns A chunks {2w,2w+1} (rows 32w..32w+31) and
    // B chunk w (rows 16w..16w+15). 1KB chunk: lane l -> row +l>>2, slot l&3.
    int rcA0 = (wid * 2) * 16 + (lane >> 2);
    int rcA1 = (wid * 2 + 1) * 16 + (lane >> 2);
    int rcB  = wid * 16 + (lane >> 2);
    int ksA0 = ((lane & 3) ^ fswz(rcA0)) * 8;
    int ksA1 = ((lane & 3) ^ fswz(rcA1)) * 8;
    int ksB  = ((lane & 3) ^ fswz(rcB)) * 8;
    long aoff0 = (arow0 + rcA0) * (long)lda + ksA0;
    long aoff1 = (arow0 + rcA1) * (long)lda + ksA1;
    long boff  = (brow0 + rcB) * (long)lda + ksB;
    int cbA0 = (wid * 2) * 512;
    int cbA1 = (wid * 2 + 1) * 512;
    int cbB  = wid * 512;

    // fragment read offsets (shorts): logical slot (lane>>4) ^ fswz(row)
    int ra[4], rb[4];
    #pragma unroll
    for (int i = 0; i < 4; ++i) {
        int rA = wm * 64 + i * 16 + l15;
        int rB = wn * 64 + i * 16 + l15;
        ra[i] = rA * 32 + (((lane >> 4) ^ fswz(rA)) * 8);
        rb[i] = rB * 32 + (((lane >> 4) ^ fswz(rB)) * 8);
    }

#define STAGE(bufi, ktoff) do { \
        gl16(A  + aoff0 + (ktoff), &As[bufi][cbA0]); \
        gl16(A  + aoff1 + (ktoff), &As[bufi][cbA1]); \
        gl16(Bt + boff  + (ktoff), &Bs[bufi][cbB]); \
    } while (0)

    int nt = kend / BK;
    // prologue: tiles 0,1 in flight (3 loads each); wait tile 0 only.
    STAGE(0, 0);
    STAGE(1, BK);
    asm volatile("s_waitcnt vmcnt(3)" ::: "memory");
    __builtin_amdgcn_sched_barrier(0);
    __builtin_amdgcn_s_barrier();

    int cur = 0;
    for (int kt = 0; kt < nt; ++kt) {
        short8 fa[4], fb[4];
        #pragma unroll
        for (int i = 0; i < 4; ++i) {
            fa[i] = *(const short8*)&As[cur][ra[i]];
            fb[i] = *(const short8*)&Bs[cur][rb[i]];
        }
        if (kt + 2 < nt) {
            // overwrite buffer (kt+2)%3 == (kt-1)%3: its readers finished
            // before iteration kt-1's barrier, which all waves have passed.
            int stg = (cur >= 1) ? cur - 1 : 2;
            STAGE(stg, (kt + 2) * BK);
            // wait: tile-(kt+1) loads landed (oldest 3 of 6) + my ds_reads
            // done (so others may overwrite As[cur] next iteration).
            asm volatile("s_waitcnt vmcnt(3) lgkmcnt(0)" ::: "memory");
            __builtin_amdgcn_sched_barrier(0);
            __builtin_amdgcn_s_barrier();
        } else if (kt + 1 < nt) {
            asm volatile("s_waitcnt vmcnt(0) lgkmcnt(0)" ::: "memory");
            __builtin_amdgcn_sched_barrier(0);
            __builtin_amdgcn_s_barrier();
        }
        __builtin_amdgcn_s_setprio(1);
        #pragma unroll
        for (int i = 0; i < 4; ++i)
            #pragma unroll
            for (int j = 0; j < 4; ++j)
                acc[i][j] = __builtin_amdgcn_mfma_f32_16x16x32_bf16(fa[i], fb[j], acc[i][j], 0, 0, 0);
        __builtin_amdgcn_s_setprio(0);
        cur = (cur >= 2) ? 0 : cur + 1;
    }
#undef STAGE

    int rq4 = (lane >> 4) * 4;
    if (wov == nullptr) {
        #pragma unroll
        for (int i = 0; i < 4; ++i) {
            #pragma unroll
            for (int j = 0; j < 4; ++j) {
                int col = bn * BN + wn * 64 + j * 16 + l15;
                float bval = bias[col];
                float wexv = wex ? wex[col] : 0.0f;
                #pragma unroll
                for (int r = 0; r < 4; ++r) {
                    long row = arow0 + wm * 64 + i * 16 + rq4 + r;
                    float v = acc[i][j][r] + bval;
                    if (wex) v += outv[row] * wexv;
                    v = fmaxf(v, 0.0f);
                    C[row * NF + col] = bf16r(v);
                }
            }
        }
    } else {
        float wv[4], bv[4];
        #pragma unroll
        for (int j = 0; j < 4; ++j) {
            int col = bn * BN + wn * 64 + j * 16 + l15;
            wv[j] = wov[col];
            bv[j] = bias[col];
        }
        float boadd = (bov != nullptr && wn == 0 && bn == 0) ? bov[0] : 0.0f;
        #pragma unroll
        for (int i = 0; i < 4; ++i) {
            #pragma unroll
            for (int r = 0; r < 4; ++r) {
                long row = arow0 + wm * 64 + i * 16 + rq4 + r;
                float s = 0.0f;
                #pragma unroll
                for (int j = 0; j < 4; ++j) {
                    int col = bn * BN + wn * 64 + j * 16 + l15;
                    float v = acc[i][j][r] + bv[j] + bf2f(Res[row * NF + col]);
                    v = fmaxf(v, 0.0f);
                    s += v * wv[j];
                }
                s += __shfl_xor(s, 1, 64);
                s += __shfl_xor(s, 2, 64);
                s += __shfl_xor(s, 4, 64);
                s += __shfl_xor(s, 8, 64);
                if (l15 == 0) atomicAdd(outp + row, s + boadd);
            }
        }
    }
}

extern "C" void kernel_launch(void* const* d_in, const int* in_sizes, int n_in,
                              void* d_out, int out_size, void* d_ws, size_t ws_size,
                              hipStream_t stream) {
    (void)in_sizes; (void)n_in; (void)out_size; (void)ws_size;
    const float* latent = (const float*)d_in[0];
    const float* pc     = (const float*)d_in[1];
    const float *wa[3], *ba[3], *wr[3], *br[3], *wo[3], *bo[3];
    for (int s = 0; s < 3; ++s) {
        int base = 2 + s * 6;
        wa[s] = (const float*)d_in[base + 0];
        ba[s] = (const float*)d_in[base + 1];
        wr[s] = (const float*)d_in[base + 2];
        br[s] = (const float*)d_in[base + 3];
        wo[s] = (const float*)d_in[base + 4];
        bo[s] = (const float*)d_in[base + 5];
    }

    char* ws = (char*)d_ws;
    size_t off = 0;
    short* A  = (short*)(ws + off); off += (size_t)M_ROWS * KP_A * 2;   // 35.7 MB
    short* H1 = (short*)(ws + off); off += (size_t)M_ROWS * NF * 2;     // 33.6 MB
    short* Wbase = (short*)(ws + off);
    short *Wta[3], *Wtr[3];
    for (int s = 0; s < 3; ++s) { Wta[s] = Wbase + (size_t)s * NF * KP_A; }
    for (int s = 0; s < 3; ++s) { Wtr[s] = Wbase + (size_t)3 * NF * KP_A + (size_t)s * NF * NF; }
    float* out = (float*)d_out;

    dim3 gw((KP_A + 31) / 32, NF / 32, 6);
    k_wt6<<<gw, 256, 0, stream>>>(wa[0], wa[1], wa[2], wr[0], wr[1], wr[2], Wbase);
    k_knncov<<<1024, 512, 0, stream>>>(pc, latent, A, bo[0], out);

    int nwg = (M_ROWS / BM) * (NF / BN);   // 512, %8==0
    for (int s = 0; s < 3; ++s) {
        if (s == 0) {
            k_gemm<<<nwg, 512, 0, stream>>>(A, Wta[0], ba[0], nullptr, H1,
                                            nullptr, nullptr, nullptr, nullptr,
                                            nullptr, KP_A, KP_A);
        } else {
            // K=512 + rank-1 (out[row] * wa_row512[col]) in epilogue
            k_gemm<<<nwg, 512, 0, stream>>>(A, Wta[s], ba[s], nullptr, H1,
                                            nullptr, nullptr,
                                            wa[s] + (size_t)NF * NF, out,
                                            nullptr, KP_A, NF);
        }
        k_gemm<<<nwg, 512, 0, stream>>>(H1, Wtr[s], br[s], H1, nullptr,
                                        wo[s], out, nullptr, nullptr,
                                        s > 0 ? bo[s] : nullptr, NF, NF);
    }
}